// Round 2
// baseline (167.837 us; speedup 1.0000x reference)
//
#include <hip/hip_runtime.h>
#include <math.h>

// Problem constants
#define L_SEQ   32768
#define H_DIM   256
#define P_DIM   128
#define P2      256      // 2*P interleaved (re,im)
#define T_CHUNK 32
#define NBLK    1024     // GEMM blocks: 32 rows each = exactly 1 chunk
#define ROWS    32       // rows per block
#define TPB     512      // 8 waves per block
#define NSEG    64       // carry segments
#define CPS     16       // chunks per segment (64*16 = 1024 chunks)

// workspace layout (float offsets)
#define WS_LB    0                      // Lambda_bar            256
#define WS_A32   256                    // Lambda_bar^32         256
#define WS_A512  512                    // Lambda_bar^512        256
#define WS_COEF  768                    // (Lb-1)/Lambda         256
#define WS_APOW  1024                   // [32][P2] Lb^{i+1}     8192
#define WS_E     9216                   // [1024][P2] chunk summ 262144
#define WS_CB    271360                 // [1024][P2] carry      262144
#define WS_PACKS 533504                 // ushort packs (float offset)
#define WS_XS    664576                 // [L][P2] xs            8388608 floats
#define WS_S     9053184                // [64][P2] segment sums 16384
#define WS_SC    9069568                // [64][P2] segment carry 16384

typedef __attribute__((ext_vector_type(8))) short short8;
typedef __attribute__((ext_vector_type(4))) float f32x4;

#define SAK 264   // LDS k-stride (ushorts) for A tile: 256 + 8 pad
#define STL 260   // LDS float stride for scan tile

// ---------------------------------------------------------------------------
// Full-precision split (RNE both halves) — used for weights.
__device__ __forceinline__ void split_bf16(float v, ushort& hi, ushort& lo) {
    union { float f; unsigned u; } a; a.f = v;
    unsigned r = a.u + 0x7FFFu + ((a.u >> 16) & 1u);   // RNE to bf16
    hi = (ushort)(r >> 16);
    union { unsigned u; float f; } hf; hf.u = ((unsigned)hi) << 16;
    float rem = v - hf.f;
    union { float f; unsigned u; } b; b.f = rem;
    unsigned r2 = b.u + 0x7FFFu + ((b.u >> 16) & 1u);
    lo = (ushort)(r2 >> 16);
}

// Fast split for A-tile staging: trunc hi (lo compensates exactly), RNE lo.
__device__ __forceinline__ void split_bf16_fast(float v, ushort& hi, ushort& lo) {
    union { float f; unsigned u; } a; a.f = v;
    hi = (ushort)(a.u >> 16);                          // trunc toward zero
    union { unsigned u; float f; } hf; hf.u = a.u & 0xFFFF0000u;
    float rem = v - hf.f;                              // exact
    union { float f; unsigned u; } b; b.f = rem;
    unsigned r2 = b.u + 0x7FFFu + ((b.u >> 16) & 1u);  // RNE lo
    lo = (ushort)(r2 >> 16);
}

// two packed complex: returns A*x + f  (layout r0,i0,r1,i1)
__device__ __forceinline__ float4 cfma2(const float4 A, const float4 x, const float4 f) {
    float4 o;
    o.x = A.x * x.x - A.y * x.y + f.x;
    o.y = A.x * x.y + A.y * x.x + f.y;
    o.z = A.z * x.z - A.w * x.w + f.z;
    o.w = A.z * x.w + A.w * x.z + f.w;
    return o;
}

// ---------------------------------------------------------------------------
// Setup 1: per-p quantities. 1 block, 128 threads.
__global__ void k_setup_p(const float* __restrict__ lre, const float* __restrict__ lim,
                          const float* __restrict__ lstep, float* __restrict__ ws) {
    int p = threadIdx.x;
    if (p >= P_DIM) return;
    float step = expf(lstep[p]);
    float lr = lre[p], li = lim[p];
    double zd = (double)lr * (double)step;
    double yd = (double)li * (double)step;
    double ed = exp(zd), cd = cos(yd), sd = sin(yd);
    double lbr = ed * cd, lbi = ed * sd;           // Lambda_bar (double)
    ws[WS_LB + 2*p]     = (float)lbr;
    ws[WS_LB + 2*p + 1] = (float)lbi;
    // Apow[i] = Lb^{i+1}, incremental
    double mr = lbr, mi = lbi;
    ws[WS_APOW + 2*p]     = (float)mr;
    ws[WS_APOW + 2*p + 1] = (float)mi;
    for (int i = 1; i < 32; i++) {
        double nr = mr * lbr - mi * lbi;
        mi = mr * lbi + mi * lbr;
        mr = nr;
        ws[WS_APOW + i*P2 + 2*p]     = (float)mr;
        ws[WS_APOW + i*P2 + 2*p + 1] = (float)mi;
    }
    // (mr,mi) == Lb^32
    ws[WS_A32 + 2*p]     = (float)mr;
    ws[WS_A32 + 2*p + 1] = (float)mi;
    // A512 = (Lb^32)^16 via 4 squarings
    double ar = mr, ai = mi;
    for (int j = 0; j < 4; j++) {
        double nr = ar*ar - ai*ai;
        ai = 2.0 * ar * ai;
        ar = nr;
    }
    ws[WS_A512 + 2*p]     = (float)ar;
    ws[WS_A512 + 2*p + 1] = (float)ai;
    // coef = (Lb - 1) / Lambda
    float lbrf = (float)lbr, lbif = (float)lbi;
    float a = lbrf - 1.0f, b = lbif;
    float den = lr*lr + li*li;
    ws[WS_COEF + 2*p]     = (a*lr + b*li) / den;
    ws[WS_COEF + 2*p + 1] = (b*lr - a*li) / den;
}

// ---------------------------------------------------------------------------
// Setup 2: build split-bf16 packed weights, layout [n][k] (k contiguous).
__global__ void k_setup_mats(const float* __restrict__ B, const float* __restrict__ C,
                             const float* __restrict__ coef,
                             ushort* __restrict__ w1h, ushort* __restrict__ w1l,
                             ushort* __restrict__ w2h, ushort* __restrict__ w2l) {
    int t = blockIdx.x * blockDim.x + threadIdx.x;   // 0..16383
    for (int e = t; e < P_DIM * H_DIM; e += 64 * 256) {
        int p = e >> 8;          // 0..127
        int h = e & 255;         // 0..255
        float br = B[(size_t)(p*H_DIM + h)*2 + 0];
        float bi = B[(size_t)(p*H_DIM + h)*2 + 1];
        float cr = coef[2*p], ci = coef[2*p + 1];
        float v1r = cr*br - ci*bi;
        float v1i = cr*bi + ci*br;
        ushort hi, lo;
        split_bf16(v1r, hi, lo);
        w1h[(size_t)(2*p)*256 + h] = hi;  w1l[(size_t)(2*p)*256 + h] = lo;
        split_bf16(v1i, hi, lo);
        w1h[(size_t)(2*p+1)*256 + h] = hi; w1l[(size_t)(2*p+1)*256 + h] = lo;
        float Cr = C[(size_t)(h*P_DIM + p)*2 + 0];
        float Ci = C[(size_t)(h*P_DIM + p)*2 + 1];
        split_bf16(2.0f*Cr, hi, lo);
        w2h[(size_t)h*256 + 2*p] = hi;    w2l[(size_t)h*256 + 2*p] = lo;
        split_bf16(-2.0f*Ci, hi, lo);
        w2h[(size_t)h*256 + 2*p+1] = hi;  w2l[(size_t)h*256 + 2*p+1] = lo;
    }
}

// ---------------------------------------------------------------------------
// Carry, two-level parallel.
__global__ void k_carry_reduce(const float* __restrict__ E, float* __restrict__ S,
                               const float* __restrict__ a32) {
    const int s = blockIdx.x;          // segment 0..63
    const int q = threadIdx.x;         // 0..63
    const float4 A = *(const float4*)(a32 + 4 * q);
    const float* xe = E + (size_t)s * CPS * P2 + 4 * q;
    float4 e = make_float4(0.f, 0.f, 0.f, 0.f);
    #pragma unroll
    for (int j = 0; j < CPS; j++)
        e = cfma2(A, e, *(const float4*)(xe + (size_t)j * P2));
    *(float4*)(S + (size_t)s * P2 + 4 * q) = e;
}

__global__ void k_carry_scan(const float* __restrict__ S, float* __restrict__ SC,
                             const float* __restrict__ a512) {
    const int q = threadIdx.x;         // 0..63
    const float4 AS = *(const float4*)(a512 + 4 * q);
    float4 c = make_float4(0.f, 0.f, 0.f, 0.f);
    #pragma unroll 8
    for (int s = 0; s < NSEG; s++) {
        *(float4*)(SC + (size_t)s * P2 + 4 * q) = c;
        c = cfma2(AS, c, *(const float4*)(S + (size_t)s * P2 + 4 * q));
    }
}

__global__ void k_carry_apply(const float* __restrict__ E, const float* __restrict__ SC,
                              float* __restrict__ cb, const float* __restrict__ a32) {
    const int s = blockIdx.x;
    const int q = threadIdx.x;
    const float4 A = *(const float4*)(a32 + 4 * q);
    const float* xe = E + (size_t)s * CPS * P2 + 4 * q;
    float* cw = cb + (size_t)s * CPS * P2 + 4 * q;
    float4 c = *(const float4*)(SC + (size_t)s * P2 + 4 * q);
    #pragma unroll
    for (int j = 0; j < CPS; j++) {
        *(float4*)(cw + (size_t)j * P2) = c;
        c = cfma2(A, c, *(const float4*)(xe + (size_t)j * P2));
    }
}

// ---------------------------------------------------------------------------
// MFMA split-bf16 GEMM: C[l][n] = sum_k A[l][k] * W[k][n]
// M=32768 (1024 blocks x 32 rows = 1 chunk), N=256 full, K=256.
// 512 threads = 8 waves; wave w owns 32-col slice [32w, 32w+32); 2mf x 2nf.
// acc = 16 VGPRs; __launch_bounds__(512,8) -> 8 waves/SIMD, 32 waves/CU.
// Epilogues route through the LDS Tile for vectorized I/O; SCAN uses a
// hierarchical 8-wave parallel scan.
template<bool EPI, bool APPLY, bool SCAN, bool BSPLIT>
__global__ __launch_bounds__(TPB, 8) void k_gemm_mfma(
        const float* __restrict__ A, const ushort* __restrict__ Wh,
        const ushort* __restrict__ Wl, float* __restrict__ Cmat,
        const float* __restrict__ Dv, const float* __restrict__ U,
        const float* __restrict__ ws, float* __restrict__ Eout,
        const float* __restrict__ cbin) {
    __shared__ float4 SMraw[2112];               // 33792 B
    ushort* Ah   = (ushort*)SMraw;               // [32][SAK]
    ushort* Al   = Ah + ROWS * SAK;
    float*  Tile = (float*)SMraw;                // [32][STL] (alias)

    const int t      = threadIdx.x;
    const int lane   = t & 63;
    const int wave   = t >> 6;        // 0..7
    const int lane16 = lane & 15;
    const int quad   = lane >> 4;
    const int blk    = blockIdx.x;
    const int l0     = blk * ROWS;

    // --- stage full A tile (32 x 256) into LDS, split bf16 ----------------
    // thread handles rows m = j*8 + wave, float4-col = lane, j = 0..3
    {
        float4 f[4];
        #pragma unroll
        for (int j = 0; j < 4; j++)
            f[j] = *(const float4*)(A + (size_t)(l0 + j*8 + wave) * 256 + lane * 4);
        if (APPLY) {
            const float4 cr = *(const float4*)(cbin + (size_t)blk * P2 + lane * 4);
            #pragma unroll
            for (int j = 0; j < 4; j++) {
                const float4 ap = *(const float4*)(ws + WS_APOW + (size_t)(j*8 + wave) * P2 + lane * 4);
                f[j] = cfma2(ap, cr, f[j]);
            }
        }
        #pragma unroll
        for (int j = 0; j < 4; j++) {
            const int m = j*8 + wave;
            ushort4 h4, l4;
            split_bf16_fast(f[j].x, h4.x, l4.x);
            split_bf16_fast(f[j].y, h4.y, l4.y);
            split_bf16_fast(f[j].z, h4.z, l4.z);
            split_bf16_fast(f[j].w, h4.w, l4.w);
            *(ushort4*)(&Ah[m * SAK + lane * 4]) = h4;
            *(ushort4*)(&Al[m * SAK + lane * 4]) = l4;
        }
    }
    __syncthreads();

    f32x4 acc[2][2];
    #pragma unroll
    for (int i = 0; i < 2; i++)
        #pragma unroll
        for (int j = 0; j < 2; j++) acc[i][j] = (f32x4){0.f, 0.f, 0.f, 0.f};

    // b-frag base: wave's 32-col slice; quads form one contiguous 64 B segment
    const ushort* WhB = Wh + (size_t)(wave * 32 + lane16) * 256 + quad * 8;
    const ushort* WlB = Wl + (size_t)(wave * 32 + lane16) * 256 + quad * 8;

    // --- K-loop: barrier-free ---------------------------------------------
    #pragma unroll
    for (int kt = 0; kt < 8; kt++) {
        const int k0 = kt * 32;
        short8 ah[2], alo[2];
        #pragma unroll
        for (int mf = 0; mf < 2; mf++) {
            int m = mf * 16 + lane16;
            ah[mf]  = *(const short8*)(&Ah[m * SAK + k0 + quad * 8]);
            alo[mf] = *(const short8*)(&Al[m * SAK + k0 + quad * 8]);
        }
        #pragma unroll
        for (int nf = 0; nf < 2; nf++) {
            short8 bh = *(const short8*)(WhB + (size_t)nf * 4096 + k0);
            short8 bl;
            if (BSPLIT) bl = *(const short8*)(WlB + (size_t)nf * 4096 + k0);
            #pragma unroll
            for (int mf = 0; mf < 2; mf++) {
                acc[mf][nf] = __builtin_amdgcn_mfma_f32_16x16x32_bf16(ah[mf],  bh, acc[mf][nf], 0, 0, 0);
                if (BSPLIT)
                    acc[mf][nf] = __builtin_amdgcn_mfma_f32_16x16x32_bf16(ah[mf], bl, acc[mf][nf], 0, 0, 0);
                acc[mf][nf] = __builtin_amdgcn_mfma_f32_16x16x32_bf16(alo[mf], bh, acc[mf][nf], 0, 0, 0);
            }
        }
    }

    // --- dump acc into LDS tile (staging dead) ----------------------------
    __syncthreads();
    #pragma unroll
    for (int mf = 0; mf < 2; mf++)
        #pragma unroll
        for (int nf = 0; nf < 2; nf++) {
            int row = mf * 16 + quad * 4;
            int col = wave * 32 + nf * 16 + lane16;
            #pragma unroll
            for (int r = 0; r < 4; r++)
                Tile[(row + r) * STL + col] = acc[mf][nf][r];
        }
    __syncthreads();

    if (!SCAN) {
        // epilogue via Tile: vectorized out = Tile + D .* U, float4 I/O
        const float4 dv = *(const float4*)(Dv + 4 * lane);
        #pragma unroll
        for (int r = 0; r < 4; r++) {
            const int row = wave * 4 + r;
            const float4 tv = *(const float4*)(Tile + row * STL + 4 * lane);
            float4 y = tv;
            if (EPI) {
                const float4 uv = *(const float4*)(U + (size_t)(l0 + row) * 256 + 4 * lane);
                y.x += dv.x * uv.x;  y.y += dv.y * uv.y;
                y.z += dv.z * uv.z;  y.w += dv.w * uv.w;
            }
            *(float4*)(Cmat + (size_t)(l0 + row) * 256 + 4 * lane) = y;
        }
    } else {
        // hierarchical parallel scan: wave w owns rows 4w..4w+3
        const float4 Alb = *(const float4*)(ws + WS_LB + 4 * lane);
        const float4 Ap0 = *(const float4*)(ws + WS_APOW + 0 * P2 + 4 * lane);  // Lb^1
        const float4 Ap1 = *(const float4*)(ws + WS_APOW + 1 * P2 + 4 * lane);  // Lb^2
        const float4 Ap2 = *(const float4*)(ws + WS_APOW + 2 * P2 + 4 * lane);  // Lb^3
        const float4 Ap3 = *(const float4*)(ws + WS_APOW + 3 * P2 + 4 * lane);  // Lb^4
        const float* Trow = Tile + (wave * 4) * STL + 4 * lane;
        // local inclusive scan of 4 rows (zero init)
        float4 v0 = *(const float4*)(Trow + 0 * STL);
        float4 v1 = cfma2(Alb, v0, *(const float4*)(Trow + 1 * STL));
        float4 v2 = cfma2(Alb, v1, *(const float4*)(Trow + 2 * STL));
        float4 v3 = cfma2(Alb, v2, *(const float4*)(Trow + 3 * STL));
        __syncthreads();
        // segment sums -> Tile rows 0..7
        *(float4*)(Tile + wave * STL + 4 * lane) = v3;
        __syncthreads();
        // wave 0: serial exclusive scan over 8 segments with Lb^4
        if (wave == 0) {
            float4 c = make_float4(0.f, 0.f, 0.f, 0.f);
            #pragma unroll
            for (int j = 0; j < 8; j++) {
                const float4 s = *(const float4*)(Tile + j * STL + 4 * lane);
                *(float4*)(Tile + (8 + j) * STL + 4 * lane) = c;
                c = cfma2(Ap3, c, s);
            }
        }
        __syncthreads();
        const float4 c = *(const float4*)(Tile + (8 + wave) * STL + 4 * lane);
        // x[4w+r] = v_r + Lb^{r+1} * c
        const float4 y0 = cfma2(Ap0, c, v0);
        const float4 y1 = cfma2(Ap1, c, v1);
        const float4 y2 = cfma2(Ap2, c, v2);
        const float4 y3 = cfma2(Ap3, c, v3);
        float* gbase = Cmat + (size_t)(l0 + wave * 4) * 256 + 4 * lane;
        *(float4*)(gbase + 0 * 256) = y0;
        *(float4*)(gbase + 1 * 256) = y1;
        *(float4*)(gbase + 2 * 256) = y2;
        *(float4*)(gbase + 3 * 256) = y3;
        if (wave == 7)
            *(float4*)(Eout + (size_t)blk * P2 + 4 * lane) = y3;
    }
}

// ---------------------------------------------------------------------------
extern "C" void kernel_launch(void* const* d_in, const int* in_sizes, int n_in,
                              void* d_out, int out_size, void* d_ws, size_t ws_size,
                              hipStream_t stream) {
    const float* lre   = (const float*)d_in[0];  // Lambda_re (P)
    const float* lim   = (const float*)d_in[1];  // Lambda_im (P)
    const float* B     = (const float*)d_in[2];  // (P,H,2)
    const float* C     = (const float*)d_in[3];  // (H,P,2)
    const float* D     = (const float*)d_in[4];  // (H)
    const float* lstep = (const float*)d_in[5];  // (P)
    const float* u     = (const float*)d_in[6];  // (L,H)
    float* out = (float*)d_out;                  // (L,H) final output only
    float* ws  = (float*)d_ws;
    float* xs  = ws + WS_XS;                     // (L,P2) scan state
    ushort* wpk = (ushort*)(ws + WS_PACKS);
    ushort* w1h = wpk;
    ushort* w1l = wpk + 65536;
    ushort* w2h = wpk + 131072;
    ushort* w2l = wpk + 196608;

    k_setup_p<<<1, 128, 0, stream>>>(lre, lim, lstep, ws);
    k_setup_mats<<<64, 256, 0, stream>>>(B, C, ws + WS_COEF, w1h, w1l, w2h, w2l);
    // GEMM1: xs_local = scan_local(u @ W1) -> ws, chunk summaries E
    k_gemm_mfma<false, false, true, true><<<NBLK, TPB, 0, stream>>>(
        u, w1h, w1l, xs, nullptr, nullptr, ws, ws + WS_E, nullptr);
    // carry across 1024 chunks: two-level parallel scan (64-way)
    k_carry_reduce<<<NSEG, 64, 0, stream>>>(ws + WS_E, ws + WS_S, ws + WS_A32);
    k_carry_scan<<<1, 64, 0, stream>>>(ws + WS_S, ws + WS_SC, ws + WS_A512);
    k_carry_apply<<<NSEG, 64, 0, stream>>>(ws + WS_E, ws + WS_SC, ws + WS_CB,
                                           ws + WS_A32);
    // GEMM2: out = (xs_local + Apow*carry) @ W2 + D*u
    k_gemm_mfma<true, true, false, false><<<NBLK, TPB, 0, stream>>>(
        xs, w2h, w2l, out, D, u, ws, nullptr, ws + WS_CB);
}

// Round 3
// 149.436 us; speedup vs baseline: 1.1231x; 1.1231x over previous
//
#include <hip/hip_runtime.h>
#include <math.h>

// Problem constants
#define L_SEQ   32768
#define H_DIM   256
#define P_DIM   128
#define P2      256      // 2*P interleaved (re,im)
#define NBLK    512      // GEMM blocks: 64 rows each = exactly 1 chunk
#define ROWS    64       // rows per block (= chunk length)
#define TPB     512      // 8 waves per block
#define NSEG    64       // carry segments
#define CPS     8        // chunks per segment (64*8 = 512 chunks)

// workspace layout (float offsets)
#define WS_LB    0                      // Lambda_bar            256
#define WS_A64   256                    // Lambda_bar^64         256
#define WS_A512  512                    // Lambda_bar^512        256
#define WS_COEF  768                    // (Lb-1)/Lambda         256
#define WS_APOW  1024                   // [64][P2] Lb^{i+1}     16384
#define WS_E     17408                  // [512][P2] chunk summ  131072
#define WS_CB    148480                 // [512][P2] carry       131072
#define WS_PACKS 279552                 // ushort packs          131072 floats
#define WS_XS    410624                 // [L][P2] xs            8388608
#define WS_S     8799232                // [64][P2] segment sums 16384
#define WS_SC    8815616                // [64][P2] segment carry 16384

typedef __attribute__((ext_vector_type(8))) short short8;
typedef __attribute__((ext_vector_type(4))) float f32x4;

#define SAK 264   // LDS k-stride (ushorts) for A tile: 256 + 8 pad
#define STL 260   // LDS float stride for scan tile

// ---------------------------------------------------------------------------
// Full-precision split (RNE both halves) — used for weights.
__device__ __forceinline__ void split_bf16(float v, ushort& hi, ushort& lo) {
    union { float f; unsigned u; } a; a.f = v;
    unsigned r = a.u + 0x7FFFu + ((a.u >> 16) & 1u);   // RNE to bf16
    hi = (ushort)(r >> 16);
    union { unsigned u; float f; } hf; hf.u = ((unsigned)hi) << 16;
    float rem = v - hf.f;
    union { float f; unsigned u; } b; b.f = rem;
    unsigned r2 = b.u + 0x7FFFu + ((b.u >> 16) & 1u);
    lo = (ushort)(r2 >> 16);
}

// Fast split for A-tile staging: trunc hi (lo compensates exactly), RNE lo.
__device__ __forceinline__ void split_bf16_fast(float v, ushort& hi, ushort& lo) {
    union { float f; unsigned u; } a; a.f = v;
    hi = (ushort)(a.u >> 16);                          // trunc toward zero
    union { unsigned u; float f; } hf; hf.u = a.u & 0xFFFF0000u;
    float rem = v - hf.f;                              // exact
    union { float f; unsigned u; } b; b.f = rem;
    unsigned r2 = b.u + 0x7FFFu + ((b.u >> 16) & 1u);  // RNE lo
    lo = (ushort)(r2 >> 16);
}

// two packed complex: returns A*x + f  (layout r0,i0,r1,i1)
__device__ __forceinline__ float4 cfma2(const float4 A, const float4 x, const float4 f) {
    float4 o;
    o.x = A.x * x.x - A.y * x.y + f.x;
    o.y = A.x * x.y + A.y * x.x + f.y;
    o.z = A.z * x.z - A.w * x.w + f.z;
    o.w = A.z * x.w + A.w * x.z + f.w;
    return o;
}

// ---------------------------------------------------------------------------
// Setup 1: per-p quantities. 1 block, 128 threads.
__global__ void k_setup_p(const float* __restrict__ lre, const float* __restrict__ lim,
                          const float* __restrict__ lstep, float* __restrict__ ws) {
    int p = threadIdx.x;
    if (p >= P_DIM) return;
    float step = expf(lstep[p]);
    float lr = lre[p], li = lim[p];
    double zd = (double)lr * (double)step;
    double yd = (double)li * (double)step;
    double ed = exp(zd), cd = cos(yd), sd = sin(yd);
    double lbr = ed * cd, lbi = ed * sd;           // Lambda_bar (double)
    ws[WS_LB + 2*p]     = (float)lbr;
    ws[WS_LB + 2*p + 1] = (float)lbi;
    // Apow[i] = Lb^{i+1}, incremental, i = 0..63
    double mr = lbr, mi = lbi;
    ws[WS_APOW + 2*p]     = (float)mr;
    ws[WS_APOW + 2*p + 1] = (float)mi;
    for (int i = 1; i < 64; i++) {
        double nr = mr * lbr - mi * lbi;
        mi = mr * lbi + mi * lbr;
        mr = nr;
        ws[WS_APOW + i*P2 + 2*p]     = (float)mr;
        ws[WS_APOW + i*P2 + 2*p + 1] = (float)mi;
    }
    // (mr,mi) == Lb^64
    ws[WS_A64 + 2*p]     = (float)mr;
    ws[WS_A64 + 2*p + 1] = (float)mi;
    // A512 = (Lb^64)^8 via 3 squarings
    double ar = mr, ai = mi;
    for (int j = 0; j < 3; j++) {
        double nr = ar*ar - ai*ai;
        ai = 2.0 * ar * ai;
        ar = nr;
    }
    ws[WS_A512 + 2*p]     = (float)ar;
    ws[WS_A512 + 2*p + 1] = (float)ai;
    // coef = (Lb - 1) / Lambda
    float lbrf = (float)lbr, lbif = (float)lbi;
    float a = lbrf - 1.0f, b = lbif;
    float den = lr*lr + li*li;
    ws[WS_COEF + 2*p]     = (a*lr + b*li) / den;
    ws[WS_COEF + 2*p + 1] = (b*lr - a*li) / den;
}

// ---------------------------------------------------------------------------
// Setup 2: build split-bf16 packed weights, layout [n][k] (k contiguous).
__global__ void k_setup_mats(const float* __restrict__ B, const float* __restrict__ C,
                             const float* __restrict__ coef,
                             ushort* __restrict__ w1h, ushort* __restrict__ w1l,
                             ushort* __restrict__ w2h, ushort* __restrict__ w2l) {
    int t = blockIdx.x * blockDim.x + threadIdx.x;   // 0..16383
    for (int e = t; e < P_DIM * H_DIM; e += 64 * 256) {
        int p = e >> 8;          // 0..127
        int h = e & 255;         // 0..255
        float br = B[(size_t)(p*H_DIM + h)*2 + 0];
        float bi = B[(size_t)(p*H_DIM + h)*2 + 1];
        float cr = coef[2*p], ci = coef[2*p + 1];
        float v1r = cr*br - ci*bi;
        float v1i = cr*bi + ci*br;
        ushort hi, lo;
        split_bf16(v1r, hi, lo);
        w1h[(size_t)(2*p)*256 + h] = hi;  w1l[(size_t)(2*p)*256 + h] = lo;
        split_bf16(v1i, hi, lo);
        w1h[(size_t)(2*p+1)*256 + h] = hi; w1l[(size_t)(2*p+1)*256 + h] = lo;
        float Cr = C[(size_t)(h*P_DIM + p)*2 + 0];
        float Ci = C[(size_t)(h*P_DIM + p)*2 + 1];
        split_bf16(2.0f*Cr, hi, lo);
        w2h[(size_t)h*256 + 2*p] = hi;    w2l[(size_t)h*256 + 2*p] = lo;
        split_bf16(-2.0f*Ci, hi, lo);
        w2h[(size_t)h*256 + 2*p+1] = hi;  w2l[(size_t)h*256 + 2*p+1] = lo;
    }
}

// ---------------------------------------------------------------------------
// Carry, two-level parallel. Chunk advance Lb^64, segment advance Lb^512.
__global__ void k_carry_reduce(const float* __restrict__ E, float* __restrict__ S,
                               const float* __restrict__ a64) {
    const int s = blockIdx.x;          // segment 0..63
    const int q = threadIdx.x;         // 0..63
    const float4 A = *(const float4*)(a64 + 4 * q);
    const float* xe = E + (size_t)s * CPS * P2 + 4 * q;
    float4 e = make_float4(0.f, 0.f, 0.f, 0.f);
    #pragma unroll
    for (int j = 0; j < CPS; j++)
        e = cfma2(A, e, *(const float4*)(xe + (size_t)j * P2));
    *(float4*)(S + (size_t)s * P2 + 4 * q) = e;
}

__global__ void k_carry_scan(const float* __restrict__ S, float* __restrict__ SC,
                             const float* __restrict__ a512) {
    const int q = threadIdx.x;         // 0..63
    const float4 AS = *(const float4*)(a512 + 4 * q);
    float4 c = make_float4(0.f, 0.f, 0.f, 0.f);
    #pragma unroll 8
    for (int s = 0; s < NSEG; s++) {
        *(float4*)(SC + (size_t)s * P2 + 4 * q) = c;
        c = cfma2(AS, c, *(const float4*)(S + (size_t)s * P2 + 4 * q));
    }
}

__global__ void k_carry_apply(const float* __restrict__ E, const float* __restrict__ SC,
                              float* __restrict__ cb, const float* __restrict__ a64) {
    const int s = blockIdx.x;
    const int q = threadIdx.x;
    const float4 A = *(const float4*)(a64 + 4 * q);
    const float* xe = E + (size_t)s * CPS * P2 + 4 * q;
    float* cw = cb + (size_t)s * CPS * P2 + 4 * q;
    float4 c = *(const float4*)(SC + (size_t)s * P2 + 4 * q);
    #pragma unroll
    for (int j = 0; j < CPS; j++) {
        *(float4*)(cw + (size_t)j * P2) = c;
        c = cfma2(A, c, *(const float4*)(xe + (size_t)j * P2));
    }
}

// ---------------------------------------------------------------------------
// MFMA split-bf16 GEMM: C[l][n] = sum_k A[l][k] * W[k][n]
// M=32768 (512 blocks x 64 rows = 1 chunk), N=256 full, K=256.
// 512 threads = 8 waves; wave w owns 32-col slice; 4 mf x 2 nf frags.
// ROWS=64 halves the per-row weight L2 traffic vs ROWS=32 (the round-2 wall).
// LDS 67.6 KB -> 2 blocks/CU, 16 waves/CU.
template<bool EPI, bool APPLY, bool SCAN, bool BSPLIT>
__global__ __launch_bounds__(TPB, 4) void k_gemm_mfma(
        const float* __restrict__ A, const ushort* __restrict__ Wh,
        const ushort* __restrict__ Wl, float* __restrict__ Cmat,
        const float* __restrict__ Dv, const float* __restrict__ U,
        const float* __restrict__ ws, float* __restrict__ Eout,
        const float* __restrict__ cbin) {
    __shared__ float4 SMraw[4224];               // 67584 B
    ushort* Ah   = (ushort*)SMraw;               // [64][SAK]
    ushort* Al   = Ah + ROWS * SAK;
    float*  Tile = (float*)SMraw;                // [64][STL] (alias, 66560 B)

    const int t      = threadIdx.x;
    const int lane   = t & 63;
    const int wave   = t >> 6;        // 0..7
    const int lane16 = lane & 15;
    const int quad   = lane >> 4;
    const int blk    = blockIdx.x;
    const int l0     = blk * ROWS;

    // --- stage full A tile (64 x 256) into LDS, split bf16 ----------------
    // thread handles rows m = j*8 + wave, float4-col = lane, j = 0..7
    {
        float4 f[8];
        #pragma unroll
        for (int j = 0; j < 8; j++)
            f[j] = *(const float4*)(A + (size_t)(l0 + j*8 + wave) * 256 + lane * 4);
        if (APPLY) {
            const float4 cr = *(const float4*)(cbin + (size_t)blk * P2 + lane * 4);
            #pragma unroll
            for (int j = 0; j < 8; j++) {
                const float4 ap = *(const float4*)(ws + WS_APOW + (size_t)(j*8 + wave) * P2 + lane * 4);
                f[j] = cfma2(ap, cr, f[j]);
            }
        }
        #pragma unroll
        for (int j = 0; j < 8; j++) {
            const int m = j*8 + wave;
            ushort4 h4, l4;
            split_bf16_fast(f[j].x, h4.x, l4.x);
            split_bf16_fast(f[j].y, h4.y, l4.y);
            split_bf16_fast(f[j].z, h4.z, l4.z);
            split_bf16_fast(f[j].w, h4.w, l4.w);
            *(ushort4*)(&Ah[m * SAK + lane * 4]) = h4;
            *(ushort4*)(&Al[m * SAK + lane * 4]) = l4;
        }
    }
    __syncthreads();

    f32x4 acc[4][2];
    #pragma unroll
    for (int i = 0; i < 4; i++)
        #pragma unroll
        for (int j = 0; j < 2; j++) acc[i][j] = (f32x4){0.f, 0.f, 0.f, 0.f};

    // b-frag base: wave's 32-col slice; quads form one contiguous 64 B segment
    const ushort* WhB = Wh + (size_t)(wave * 32 + lane16) * 256 + quad * 8;
    const ushort* WlB = Wl + (size_t)(wave * 32 + lane16) * 256 + quad * 8;

    // --- K-loop: barrier-free ---------------------------------------------
    #pragma unroll
    for (int kt = 0; kt < 8; kt++) {
        const int k0 = kt * 32;
        short8 ah[4], alo[4];
        #pragma unroll
        for (int mf = 0; mf < 4; mf++) {
            int m = mf * 16 + lane16;
            ah[mf]  = *(const short8*)(&Ah[m * SAK + k0 + quad * 8]);
            alo[mf] = *(const short8*)(&Al[m * SAK + k0 + quad * 8]);
        }
        #pragma unroll
        for (int nf = 0; nf < 2; nf++) {
            short8 bh = *(const short8*)(WhB + (size_t)nf * 4096 + k0);
            short8 bl;
            if (BSPLIT) bl = *(const short8*)(WlB + (size_t)nf * 4096 + k0);
            #pragma unroll
            for (int mf = 0; mf < 4; mf++) {
                acc[mf][nf] = __builtin_amdgcn_mfma_f32_16x16x32_bf16(ah[mf],  bh, acc[mf][nf], 0, 0, 0);
                if (BSPLIT)
                    acc[mf][nf] = __builtin_amdgcn_mfma_f32_16x16x32_bf16(ah[mf], bl, acc[mf][nf], 0, 0, 0);
                acc[mf][nf] = __builtin_amdgcn_mfma_f32_16x16x32_bf16(alo[mf], bh, acc[mf][nf], 0, 0, 0);
            }
        }
    }

    // --- dump acc into LDS tile (staging dead) ----------------------------
    __syncthreads();
    #pragma unroll
    for (int mf = 0; mf < 4; mf++)
        #pragma unroll
        for (int nf = 0; nf < 2; nf++) {
            int row = mf * 16 + quad * 4;
            int col = wave * 32 + nf * 16 + lane16;
            #pragma unroll
            for (int r = 0; r < 4; r++)
                Tile[(row + r) * STL + col] = acc[mf][nf][r];
        }
    __syncthreads();

    if (!SCAN) {
        // epilogue via Tile: vectorized out = Tile + D .* U, float4 I/O
        const float4 dv = *(const float4*)(Dv + 4 * lane);
        #pragma unroll
        for (int r = 0; r < 8; r++) {
            const int row = wave * 8 + r;
            const float4 tv = *(const float4*)(Tile + row * STL + 4 * lane);
            float4 y = tv;
            if (EPI) {
                const float4 uv = *(const float4*)(U + (size_t)(l0 + row) * 256 + 4 * lane);
                y.x += dv.x * uv.x;  y.y += dv.y * uv.y;
                y.z += dv.z * uv.z;  y.w += dv.w * uv.w;
            }
            *(float4*)(Cmat + (size_t)(l0 + row) * 256 + 4 * lane) = y;
        }
    } else {
        // hierarchical parallel scan: wave w owns rows 8w..8w+7
        const float4 Alb = *(const float4*)(ws + WS_LB + 4 * lane);
        const float* Trow = Tile + (wave * 8) * STL + 4 * lane;
        float4 v[8];
        float4 x = make_float4(0.f, 0.f, 0.f, 0.f);
        #pragma unroll
        for (int r = 0; r < 8; r++) {
            x = cfma2(Alb, x, *(const float4*)(Trow + r * STL));
            v[r] = x;
        }
        __syncthreads();
        // segment sums -> Tile rows 0..7
        *(float4*)(Tile + wave * STL + 4 * lane) = v[7];
        __syncthreads();
        // wave 0: serial exclusive scan over 8 segments with Lb^8 = Apow[7]
        if (wave == 0) {
            const float4 A8 = *(const float4*)(ws + WS_APOW + 7 * P2 + 4 * lane);
            float4 c = make_float4(0.f, 0.f, 0.f, 0.f);
            #pragma unroll
            for (int j = 0; j < 8; j++) {
                const float4 s = *(const float4*)(Tile + j * STL + 4 * lane);
                *(float4*)(Tile + (8 + j) * STL + 4 * lane) = c;
                c = cfma2(A8, c, s);
            }
        }
        __syncthreads();
        const float4 c = *(const float4*)(Tile + (8 + wave) * STL + 4 * lane);
        // x[8w+r] = v_r + Lb^{r+1} * c ; store immediately
        float* gbase = Cmat + (size_t)(l0 + wave * 8) * 256 + 4 * lane;
        #pragma unroll
        for (int r = 0; r < 8; r++) {
            const float4 ap = *(const float4*)(ws + WS_APOW + (size_t)r * P2 + 4 * lane);
            const float4 y = cfma2(ap, c, v[r]);
            *(float4*)(gbase + (size_t)r * 256) = y;
            if (r == 7 && wave == 7)
                *(float4*)(Eout + (size_t)blk * P2 + 4 * lane) = y;
        }
    }
}

// ---------------------------------------------------------------------------
extern "C" void kernel_launch(void* const* d_in, const int* in_sizes, int n_in,
                              void* d_out, int out_size, void* d_ws, size_t ws_size,
                              hipStream_t stream) {
    const float* lre   = (const float*)d_in[0];  // Lambda_re (P)
    const float* lim   = (const float*)d_in[1];  // Lambda_im (P)
    const float* B     = (const float*)d_in[2];  // (P,H,2)
    const float* C     = (const float*)d_in[3];  // (H,P,2)
    const float* D     = (const float*)d_in[4];  // (H)
    const float* lstep = (const float*)d_in[5];  // (P)
    const float* u     = (const float*)d_in[6];  // (L,H)
    float* out = (float*)d_out;                  // (L,H) final output only
    float* ws  = (float*)d_ws;
    float* xs  = ws + WS_XS;                     // (L,P2) scan state
    ushort* wpk = (ushort*)(ws + WS_PACKS);
    ushort* w1h = wpk;
    ushort* w1l = wpk + 65536;
    ushort* w2h = wpk + 131072;
    ushort* w2l = wpk + 196608;

    k_setup_p<<<1, 128, 0, stream>>>(lre, lim, lstep, ws);
    k_setup_mats<<<64, 256, 0, stream>>>(B, C, ws + WS_COEF, w1h, w1l, w2h, w2l);
    // GEMM1: xs_local = scan_local(u @ W1) -> ws, chunk summaries E
    k_gemm_mfma<false, false, true, true><<<NBLK, TPB, 0, stream>>>(
        u, w1h, w1l, xs, nullptr, nullptr, ws, ws + WS_E, nullptr);
    // carry across 512 chunks: two-level parallel scan (64-way)
    k_carry_reduce<<<NSEG, 64, 0, stream>>>(ws + WS_E, ws + WS_S, ws + WS_A64);
    k_carry_scan<<<1, 64, 0, stream>>>(ws + WS_S, ws + WS_SC, ws + WS_A512);
    k_carry_apply<<<NSEG, 64, 0, stream>>>(ws + WS_E, ws + WS_SC, ws + WS_CB,
                                           ws + WS_A64);
    // GEMM2: out = (xs_local + Apow*carry) @ W2 + D*u
    k_gemm_mfma<true, true, false, false><<<NBLK, TPB, 0, stream>>>(
        xs, w2h, w2l, out, D, u, ws, nullptr, ws + WS_CB);
}